// Round 7
// baseline (304.383 us; speedup 1.0000x reference)
//
#include <hip/hip_runtime.h>
#include <math.h>

#define DIM 128
#define NA 8192
#define CAP 64
#define NF (NA*DIM)

// ============ k1: gathers + transposes + zero accumulators/counters/degcol ============
__global__ __launch_bounds__(256) void k_prep(
    const int* __restrict__ fp, const int* __restrict__ words,
    const float* __restrict__ emb_fp, const float* __restrict__ emb_w,
    const float* __restrict__ Wg, const float* __restrict__ Wa,
    float* __restrict__ xs, float* __restrict__ xsp,
    float* __restrict__ WgT, float* __restrict__ WaT,
    float* __restrict__ xc, float* __restrict__ xp,
    int* __restrict__ degcol, int* __restrict__ ctrs) {
  int b = blockIdx.x, tid = threadIdx.x;
  if (b < 1024) {                       // gather atom embeddings
    int i = b * 256 + tid;
    int row = i >> 5, c4 = i & 31;
    ((float4*)(xs + (size_t)row * DIM))[c4] =
        ((const float4*)(emb_fp + (size_t)fp[row] * DIM))[c4];
  } else if (b < 2048) {                // gather word embeddings
    int i = (b - 1024) * 256 + tid;
    int row = i >> 5, c4 = i & 31;
    ((float4*)(xsp + (size_t)row * DIM))[c4] =
        ((const float4*)(emb_w + (size_t)words[row] * DIM))[c4];
  } else if (b < 2112) {                // transpose Wg[0..2], Wa (32x32 tiles)
    __shared__ float tile[32][33];
    int sub = b - 2048;
    int m = sub >> 4, t = sub & 15;
    int tx = t & 3, ty = t >> 2;
    const float* src = (m < 3) ? Wg + m * DIM * DIM : Wa;
    float*       dst = (m < 3) ? WgT + m * DIM * DIM : WaT;
    int x = tid & 31, y0 = tid >> 5;
    int xg = tx * 32 + x;
    for (int i = y0; i < 32; i += 8)
      tile[i][x] = src[(ty * 32 + i) * DIM + xg];
    __syncthreads();
    int xo = ty * 32 + x;
    for (int i = y0; i < 32; i += 8)
      dst[(tx * 32 + i) * DIM + xo] = tile[x][i];
  } else if (b == 2112) {               // zero small accumulators + counters
    if (tid < DIM) { xc[tid] = 0.f; xp[tid] = 0.f; }
    if (tid == 0) { ctrs[0] = 0; ctrs[1] = 0; }
  } else {                              // zero degcol (8 blocks x 256 x int4)
    int i = (b - 2113) * 256 + tid;
    int4 z; z.x = 0; z.y = 0; z.z = 0; z.w = 0;
    ((int4*)degcol)[i] = z;
  }
}

// ============ k2: ELL+degcol scan (HBM floor) + GNN gemm0 + prot conv0/gemm0 hidden under it ============
__global__ __launch_bounds__(512) void k_scan(
    const float* __restrict__ adj,
    const float* __restrict__ WgT, const float* __restrict__ bg,
    const float* __restrict__ xs, float* __restrict__ hs0,
    const float* __restrict__ xsp0, const float* __restrict__ cw,
    const float* __restrict__ cb, const float* __restrict__ WaT,
    const float* __restrict__ ba, float* __restrict__ hs2p0,
    int* __restrict__ ell, int* __restrict__ cnt, int* __restrict__ degcol) {
  __shared__ float U[54 * 156];
  __shared__ float wl[529];
  __shared__ float As[32 * 132];
  int b = blockIdx.x, tid = threadIdx.x;

  if (b < 256) {
    // ---- GNN gemm0: hs0 = relu(xs @ Wg0^T + bg0), 32 rows ----
    size_t rbase = (size_t)b * 32;
    for (int i = tid; i < 1024; i += 512) {
      int r = i >> 5, c = i & 31;
      *(float4*)&As[r * 132 + c * 4] = *(const float4*)&xs[(rbase + r) * DIM + c * 4];
    }
    __syncthreads();
    int rg = tid >> 5, j0 = (tid & 31) * 4;
    float acc[2][4];
    float4 b4 = *(const float4*)&bg[j0];
    acc[0][0] = acc[1][0] = b4.x; acc[0][1] = acc[1][1] = b4.y;
    acc[0][2] = acc[1][2] = b4.z; acc[0][3] = acc[1][3] = b4.w;
    for (int k4 = 0; k4 < 32; ++k4) {
      float a0[4], a1[4];
      *(float4*)a0 = *(float4*)&As[(rg * 2) * 132 + k4 * 4];
      *(float4*)a1 = *(float4*)&As[(rg * 2 + 1) * 132 + k4 * 4];
      #pragma unroll
      for (int kk = 0; kk < 4; ++kk) {
        float4 w4 = *(const float4*)&WgT[(k4 * 4 + kk) * DIM + j0];
        float w[4] = {w4.x, w4.y, w4.z, w4.w};
        #pragma unroll
        for (int c = 0; c < 4; ++c) {
          acc[0][c] += a0[kk] * w[c];
          acc[1][c] += a1[kk] * w[c];
        }
      }
    }
    #pragma unroll
    for (int rr = 0; rr < 2; ++rr) {
      float4 o;
      o.x = fmaxf(acc[rr][0], 0.f); o.y = fmaxf(acc[rr][1], 0.f);
      o.z = fmaxf(acc[rr][2], 0.f); o.w = fmaxf(acc[rr][3], 0.f);
      *(float4*)&hs0[(rbase + rg * 2 + rr) * DIM + j0] = o;
    }
  } else if (b < 512) {
    // ---- protein layer0: conv(xsp0) -> gemm -> hs2p0, 32 rows ----
    int blk = b - 256;
    int l0 = blk * 32;
    for (int i = tid; i < 529; i += 512) wl[i] = cw[i];
    for (int i = tid; i < 54 * 156; i += 512) {
      int ll = i / 156, dd = i % 156;
      int gl = l0 - 11 + ll, gd = dd - 11;
      float v = 0.f;
      if (gl >= 0 && gl < NA && (unsigned)gd < DIM)
        v = xsp0[(size_t)gl * DIM + gd];
      U[i] = v;
    }
    __syncthreads();
    {
      int ro = tid >> 4, d0 = (tid & 15) * 8;
      float a8[8];
      #pragma unroll
      for (int m = 0; m < 8; ++m) a8[m] = 0.f;
      for (int a = 0; a < 23; ++a) {
        float r[30];
        #pragma unroll
        for (int q = 0; q < 7; ++q)
          *(float4*)&r[4 * q] = *(const float4*)&U[(ro + a) * 156 + d0 + 4 * q];
        r[28] = U[(ro + a) * 156 + d0 + 28];
        r[29] = U[(ro + a) * 156 + d0 + 29];
        #pragma unroll
        for (int bb = 0; bb < 23; ++bb) {
          float wb = wl[a * 23 + bb];
          #pragma unroll
          for (int m = 0; m < 8; ++m) a8[m] += r[bb + m] * wb;
        }
      }
      float cbias = cb[0];
      #pragma unroll
      for (int m = 0; m < 8; ++m)
        As[ro * 132 + d0 + m] = fmaxf(a8[m] + cbias, 0.f);
    }
    __syncthreads();
    {
      int rg = tid >> 5, j0 = (tid & 31) * 4;
      float acc[2][4];
      float4 b4 = *(const float4*)&ba[j0];
      acc[0][0] = acc[1][0] = b4.x; acc[0][1] = acc[1][1] = b4.y;
      acc[0][2] = acc[1][2] = b4.z; acc[0][3] = acc[1][3] = b4.w;
      for (int k4 = 0; k4 < 32; ++k4) {
        float a0[4], a1[4];
        *(float4*)a0 = *(float4*)&As[(rg * 2) * 132 + k4 * 4];
        *(float4*)a1 = *(float4*)&As[(rg * 2 + 1) * 132 + k4 * 4];
        #pragma unroll
        for (int kk = 0; kk < 4; ++kk) {
          float4 w4 = *(const float4*)&WaT[(k4 * 4 + kk) * DIM + j0];
          float w[4] = {w4.x, w4.y, w4.z, w4.w};
          #pragma unroll
          for (int c = 0; c < 4; ++c) {
            acc[0][c] += a0[kk] * w[c];
            acc[1][c] += a1[kk] * w[c];
          }
        }
      }
      #pragma unroll
      for (int rr = 0; rr < 2; ++rr) {
        float4 o;
        o.x = fmaxf(acc[rr][0], 0.f); o.y = fmaxf(acc[rr][1], 0.f);
        o.z = fmaxf(acc[rr][2], 0.f); o.w = fmaxf(acc[rr][3], 0.f);
        *(float4*)&hs2p0[((size_t)l0 + rg * 2 + rr) * DIM + j0] = o;
      }
    }
  } else {
    // ---- ELL + degcol scan: 8 waves, 1 row/wave, 8-deep prefetch ----
    int wv = tid >> 6, lane = tid & 63;
    int row = (b - 512) * 8 + wv;
    const float4* rp = (const float4*)(adj + (size_t)row * NA);
    int* er = ell + (size_t)row * CAP;
    int c = 0;
    float4 buf[8];
    #pragma unroll
    for (int u = 0; u < 8; ++u) buf[u] = rp[u * 64 + lane];
    for (int it = 0; it < 32; it += 8) {
      float4 nb[8];
      if (it + 8 < 32) {
        #pragma unroll
        for (int u = 0; u < 8; ++u) nb[u] = rp[(it + 8 + u) * 64 + lane];
      }
      #pragma unroll
      for (int u = 0; u < 8; ++u) {
        float f[4] = {buf[u].x, buf[u].y, buf[u].z, buf[u].w};
        #pragma unroll
        for (int j = 0; j < 4; ++j) {
          bool nz = (f[j] != 0.0f);
          unsigned long long m = __ballot(nz);
          if (nz) {
            int col = (it + u) * 256 + lane * 4 + j;
            int pos = c + __popcll(m & ((1ull << lane) - 1ull));
            if (pos < CAP) er[pos] = col;
            atomicAdd(&degcol[col], 1);
          }
          c += __popcll(m);
        }
      }
      #pragma unroll
      for (int u = 0; u < 8; ++u) buf[u] = nb[u];
    }
    if (lane == 0) cnt[row] = c > CAP ? CAP : c;
  }
}

// ============ k3: spmv0 (xs += A@hs0, own 16 rows) + gemm1 (hs1) ============
__global__ __launch_bounds__(512) void k_gnn1(
    const int* __restrict__ ell, const int* __restrict__ cnt,
    const float* __restrict__ hs0, float* __restrict__ xs,
    const float* __restrict__ WgT1, const float* __restrict__ bg1,
    float* __restrict__ hs1) {
  __shared__ float As[16 * 132];
  int tid = threadIdx.x;
  int wv = tid >> 6, lane = tid & 63;
  size_t rbase = (size_t)blockIdx.x * 16;
  for (int rr = 0; rr < 2; ++rr) {
    int lr = wv * 2 + rr;
    size_t row = rbase + lr;
    int n = cnt[row];
    const int* er = ell + row * CAP;
    float2 a2 = *(const float2*)&xs[row * DIM + lane * 2];
    int t = 0;
    for (; t + 4 <= n; t += 4) {
      int j0 = er[t], j1 = er[t + 1], j2 = er[t + 2], j3 = er[t + 3];
      float2 h0 = *(const float2*)&hs0[(size_t)j0 * DIM + lane * 2];
      float2 h1 = *(const float2*)&hs0[(size_t)j1 * DIM + lane * 2];
      float2 h2 = *(const float2*)&hs0[(size_t)j2 * DIM + lane * 2];
      float2 h3 = *(const float2*)&hs0[(size_t)j3 * DIM + lane * 2];
      a2.x += (h0.x + h1.x) + (h2.x + h3.x);
      a2.y += (h0.y + h1.y) + (h2.y + h3.y);
    }
    for (; t < n; ++t) {
      float2 h = *(const float2*)&hs0[(size_t)er[t] * DIM + lane * 2];
      a2.x += h.x; a2.y += h.y;
    }
    *(float2*)&xs[row * DIM + lane * 2] = a2;      // xs_1 (needed by k4)
    As[lr * 132 + lane * 2] = a2.x;
    As[lr * 132 + lane * 2 + 1] = a2.y;
  }
  __syncthreads();
  // gemm1: 1 row x 4 cols per thread-group
  int rg = tid >> 5, j0 = (tid & 31) * 4;
  float acc[4];
  float4 b4 = *(const float4*)&bg1[j0];
  acc[0] = b4.x; acc[1] = b4.y; acc[2] = b4.z; acc[3] = b4.w;
  for (int k4 = 0; k4 < 32; ++k4) {
    float a[4];
    *(float4*)a = *(float4*)&As[rg * 132 + k4 * 4];
    #pragma unroll
    for (int kk = 0; kk < 4; ++kk) {
      float4 w4 = *(const float4*)&WgT1[(k4 * 4 + kk) * DIM + j0];
      acc[0] += a[kk] * w4.x; acc[1] += a[kk] * w4.y;
      acc[2] += a[kk] * w4.z; acc[3] += a[kk] * w4.w;
    }
  }
  float4 o;
  o.x = fmaxf(acc[0], 0.f); o.y = fmaxf(acc[1], 0.f);
  o.z = fmaxf(acc[2], 0.f); o.w = fmaxf(acc[3], 0.f);
  *(float4*)&hs1[(rbase + rg) * DIM + j0] = o;
}

// ============ k4: spmv1 + gemm2 + degcol-weighted colsum -> xc; last block: xchain ============
__global__ __launch_bounds__(512) void k_gnn2(
    const int* __restrict__ ell, const int* __restrict__ cnt,
    const float* __restrict__ hs1, const float* __restrict__ xs,
    const float* __restrict__ WgT2, const float* __restrict__ bg2,
    const int* __restrict__ degcol, float* __restrict__ xc,
    const float* __restrict__ WaT, const float* __restrict__ ba,
    float* __restrict__ xall, int* __restrict__ ctr) {
  __shared__ float As[16 * 132];
  __shared__ float H2[16 * 132];
  __shared__ float red[4 * DIM];
  __shared__ float xb[DIM];
  __shared__ int lastf;
  int tid = threadIdx.x;
  int wv = tid >> 6, lane = tid & 63;
  size_t rbase = (size_t)blockIdx.x * 16;
  // spmv1 -> As (xs_2, block-local only)
  for (int rr = 0; rr < 2; ++rr) {
    int lr = wv * 2 + rr;
    size_t row = rbase + lr;
    int n = cnt[row];
    const int* er = ell + row * CAP;
    float2 a2 = *(const float2*)&xs[row * DIM + lane * 2];
    int t = 0;
    for (; t + 4 <= n; t += 4) {
      int j0 = er[t], j1 = er[t + 1], j2 = er[t + 2], j3 = er[t + 3];
      float2 h0 = *(const float2*)&hs1[(size_t)j0 * DIM + lane * 2];
      float2 h1 = *(const float2*)&hs1[(size_t)j1 * DIM + lane * 2];
      float2 h2 = *(const float2*)&hs1[(size_t)j2 * DIM + lane * 2];
      float2 h3 = *(const float2*)&hs1[(size_t)j3 * DIM + lane * 2];
      a2.x += (h0.x + h1.x) + (h2.x + h3.x);
      a2.y += (h0.y + h1.y) + (h2.y + h3.y);
    }
    for (; t < n; ++t) {
      float2 h = *(const float2*)&hs1[(size_t)er[t] * DIM + lane * 2];
      a2.x += h.x; a2.y += h.y;
    }
    As[lr * 132 + lane * 2] = a2.x;
    As[lr * 132 + lane * 2 + 1] = a2.y;
  }
  __syncthreads();
  // gemm2 -> H2 (hs_2, block-local only)
  {
    int rg = tid >> 5, j0 = (tid & 31) * 4;
    float acc[4];
    float4 b4 = *(const float4*)&bg2[j0];
    acc[0] = b4.x; acc[1] = b4.y; acc[2] = b4.z; acc[3] = b4.w;
    for (int k4 = 0; k4 < 32; ++k4) {
      float a[4];
      *(float4*)a = *(float4*)&As[rg * 132 + k4 * 4];
      #pragma unroll
      for (int kk = 0; kk < 4; ++kk) {
        float4 w4 = *(const float4*)&WgT2[(k4 * 4 + kk) * DIM + j0];
        acc[0] += a[kk] * w4.x; acc[1] += a[kk] * w4.y;
        acc[2] += a[kk] * w4.z; acc[3] += a[kk] * w4.w;
      }
    }
    H2[rg * 132 + j0]     = fmaxf(acc[0], 0.f);
    H2[rg * 132 + j0 + 1] = fmaxf(acc[1], 0.f);
    H2[rg * 132 + j0 + 2] = fmaxf(acc[2], 0.f);
    H2[rg * 132 + j0 + 3] = fmaxf(acc[3], 0.f);
  }
  __syncthreads();
  // colsum: xc += sum_own(xs_2[r] + degcol[r]*hs_2[r])
  {
    int c = tid & 127, h = tid >> 7;
    float s = 0.f;
    #pragma unroll
    for (int q = 0; q < 4; ++q) {
      int r = h + q * 4;
      float dg = (float)degcol[rbase + r];
      s += As[r * 132 + c] + dg * H2[r * 132 + c];
    }
    red[h * DIM + c] = s;
    __syncthreads();
    if (h == 0)
      atomicAdd(&xc[c], red[c] + red[DIM + c] + red[2 * DIM + c] + red[3 * DIM + c]);
  }
  // last-block xchain
  __threadfence();
  __syncthreads();
  if (tid == 0) lastf = (atomicAdd(ctr, 1) == (int)gridDim.x - 1);
  __syncthreads();
  if (lastf) {
    __threadfence();
    if (tid < DIM) xb[tid] = atomicAdd(&xc[tid], 0.0f);   // coherent read
    __syncthreads();
    for (int i = 0; i < 3; ++i) {
      float a = 0.f;
      if (tid < DIM) {
        a = ba[tid];
        for (int k = 0; k < DIM; ++k) a += xb[k] * WaT[k * DIM + tid];
        a = fmaxf(a, 0.f);
      }
      __syncthreads();
      if (tid < DIM) { xb[tid] = a; xall[i * DIM + tid] = a; }
      __syncthreads();
    }
  }
}

// ============ k5: protein layer1: attn0(halo) -> conv1 -> gemm1 -> hs2p1 ============
__global__ __launch_bounds__(512) void k_prot1(
    const float* __restrict__ hs2p0, const float* __restrict__ xall,
    const float* __restrict__ cw1, const float* __restrict__ cb1,
    const float* __restrict__ WaT, const float* __restrict__ ba,
    float* __restrict__ hs2p1) {
  __shared__ float U[54 * 156];
  __shared__ float wl[529];
  __shared__ float As[32 * 132];
  __shared__ float w54[56];
  __shared__ float xrow[DIM];
  int tid = threadIdx.x;
  int wv = tid >> 6, lane = tid & 63;
  int l0 = blockIdx.x * 32;
  // stage hs2p0 halo into tile (cols 11..138), zero pads
  for (int i = tid; i < 529; i += 512) wl[i] = cw1[i];
  if (tid < DIM) xrow[tid] = xall[tid];             // x_0 (first updated x)
  for (int i = tid; i < 54 * 156; i += 512) {
    int ll = i / 156, dd = i % 156;
    int gl = l0 - 11 + ll, gd = dd - 11;
    float v = 0.f;
    if (gl >= 0 && gl < NA && (unsigned)gd < DIM)
      v = hs2p0[(size_t)gl * DIM + gd];
    U[i] = v;
  }
  __syncthreads();
  // attn weights for all 54 halo rows
  for (int ll = wv; ll < 54; ll += 8) {
    float p = U[ll * 156 + 11 + lane * 2] * xrow[lane * 2]
            + U[ll * 156 + 12 + lane * 2] * xrow[lane * 2 + 1];
    #pragma unroll
    for (int s = 32; s > 0; s >>= 1) p += __shfl_xor(p, s, 64);
    if (lane == 0) w54[ll] = tanhf(p);
  }
  __syncthreads();
  // scale tile rows by tanh weight -> xsp1 in LDS
  for (int i = tid; i < 54 * 128; i += 512) {
    int ll = i >> 7, dd = i & 127;
    U[ll * 156 + 11 + dd] *= w54[ll];
  }
  __syncthreads();
  // conv1
  {
    int ro = tid >> 4, d0 = (tid & 15) * 8;
    float a8[8];
    #pragma unroll
    for (int m = 0; m < 8; ++m) a8[m] = 0.f;
    for (int a = 0; a < 23; ++a) {
      float r[30];
      #pragma unroll
      for (int q = 0; q < 7; ++q)
        *(float4*)&r[4 * q] = *(const float4*)&U[(ro + a) * 156 + d0 + 4 * q];
      r[28] = U[(ro + a) * 156 + d0 + 28];
      r[29] = U[(ro + a) * 156 + d0 + 29];
      #pragma unroll
      for (int bb = 0; bb < 23; ++bb) {
        float wb = wl[a * 23 + bb];
        #pragma unroll
        for (int m = 0; m < 8; ++m) a8[m] += r[bb + m] * wb;
      }
    }
    float cbias = cb1[0];
    #pragma unroll
    for (int m = 0; m < 8; ++m)
      As[ro * 132 + d0 + m] = fmaxf(a8[m] + cbias, 0.f);
  }
  __syncthreads();
  // gemm1 -> hs2p1
  {
    int rg = tid >> 5, j0 = (tid & 31) * 4;
    float acc[2][4];
    float4 b4 = *(const float4*)&ba[j0];
    acc[0][0] = acc[1][0] = b4.x; acc[0][1] = acc[1][1] = b4.y;
    acc[0][2] = acc[1][2] = b4.z; acc[0][3] = acc[1][3] = b4.w;
    for (int k4 = 0; k4 < 32; ++k4) {
      float a0[4], a1[4];
      *(float4*)a0 = *(float4*)&As[(rg * 2) * 132 + k4 * 4];
      *(float4*)a1 = *(float4*)&As[(rg * 2 + 1) * 132 + k4 * 4];
      #pragma unroll
      for (int kk = 0; kk < 4; ++kk) {
        float4 w4 = *(const float4*)&WaT[(k4 * 4 + kk) * DIM + j0];
        float w[4] = {w4.x, w4.y, w4.z, w4.w};
        #pragma unroll
        for (int c = 0; c < 4; ++c) {
          acc[0][c] += a0[kk] * w[c];
          acc[1][c] += a1[kk] * w[c];
        }
      }
    }
    #pragma unroll
    for (int rr = 0; rr < 2; ++rr) {
      float4 o;
      o.x = fmaxf(acc[rr][0], 0.f); o.y = fmaxf(acc[rr][1], 0.f);
      o.z = fmaxf(acc[rr][2], 0.f); o.w = fmaxf(acc[rr][3], 0.f);
      *(float4*)&hs2p1[((size_t)l0 + rg * 2 + rr) * DIM + j0] = o;
    }
  }
}

// ============ k6: protein layer2 + attn2-colsum -> xp; last block: final softmax ============
__global__ __launch_bounds__(512) void k_prot2(
    const float* __restrict__ hs2p1, const float* __restrict__ xall,
    const float* __restrict__ cw2, const float* __restrict__ cb2,
    const float* __restrict__ WaT, const float* __restrict__ ba,
    float* __restrict__ xp, const float* __restrict__ xc,
    const float* __restrict__ Wo, const float* __restrict__ bo,
    float* __restrict__ out, int* __restrict__ ctr) {
  __shared__ float U[54 * 156];        // tile, later H2[32][132]
  __shared__ float wl[529];
  __shared__ float As[32 * 132];
  __shared__ float w54[56];
  __shared__ float xrow[DIM];
  __shared__ float red[4 * DIM];
  __shared__ float fs[32];
  __shared__ int lastf;
  int tid = threadIdx.x;
  int wv = tid >> 6, lane = tid & 63;
  int l0 = blockIdx.x * 32;
  float* H2 = U;                       // reuse after conv

  for (int i = tid; i < 529; i += 512) wl[i] = cw2[i];
  if (tid < DIM) xrow[tid] = xall[DIM + tid];       // x_1
  for (int i = tid; i < 54 * 156; i += 512) {
    int ll = i / 156, dd = i % 156;
    int gl = l0 - 11 + ll, gd = dd - 11;
    float v = 0.f;
    if (gl >= 0 && gl < NA && (unsigned)gd < DIM)
      v = hs2p1[(size_t)gl * DIM + gd];
    U[i] = v;
  }
  __syncthreads();
  for (int ll = wv; ll < 54; ll += 8) {
    float p = U[ll * 156 + 11 + lane * 2] * xrow[lane * 2]
            + U[ll * 156 + 12 + lane * 2] * xrow[lane * 2 + 1];
    #pragma unroll
    for (int s = 32; s > 0; s >>= 1) p += __shfl_xor(p, s, 64);
    if (lane == 0) w54[ll] = tanhf(p);
  }
  __syncthreads();
  for (int i = tid; i < 54 * 128; i += 512) {
    int ll = i >> 7, dd = i & 127;
    U[ll * 156 + 11 + dd] *= w54[ll];
  }
  __syncthreads();
  {
    int ro = tid >> 4, d0 = (tid & 15) * 8;
    float a8[8];
    #pragma unroll
    for (int m = 0; m < 8; ++m) a8[m] = 0.f;
    for (int a = 0; a < 23; ++a) {
      float r[30];
      #pragma unroll
      for (int q = 0; q < 7; ++q)
        *(float4*)&r[4 * q] = *(const float4*)&U[(ro + a) * 156 + d0 + 4 * q];
      r[28] = U[(ro + a) * 156 + d0 + 28];
      r[29] = U[(ro + a) * 156 + d0 + 29];
      #pragma unroll
      for (int bb = 0; bb < 23; ++bb) {
        float wb = wl[a * 23 + bb];
        #pragma unroll
        for (int m = 0; m < 8; ++m) a8[m] += r[bb + m] * wb;
      }
    }
    float cbias = cb2[0];
    #pragma unroll
    for (int m = 0; m < 8; ++m)
      As[ro * 132 + d0 + m] = fmaxf(a8[m] + cbias, 0.f);
  }
  __syncthreads();    // conv done reading U; H2 may overwrite
  {
    int rg = tid >> 5, j0 = (tid & 31) * 4;
    float acc[2][4];
    float4 b4 = *(const float4*)&ba[j0];
    acc[0][0] = acc[1][0] = b4.x; acc[0][1] = acc[1][1] = b4.y;
    acc[0][2] = acc[1][2] = b4.z; acc[0][3] = acc[1][3] = b4.w;
    for (int k4 = 0; k4 < 32; ++k4) {
      float a0[4], a1[4];
      *(float4*)a0 = *(float4*)&As[(rg * 2) * 132 + k4 * 4];
      *(float4*)a1 = *(float4*)&As[(rg * 2 + 1) * 132 + k4 * 4];
      #pragma unroll
      for (int kk = 0; kk < 4; ++kk) {
        float4 w4 = *(const float4*)&WaT[(k4 * 4 + kk) * DIM + j0];
        float w[4] = {w4.x, w4.y, w4.z, w4.w};
        #pragma unroll
        for (int c = 0; c < 4; ++c) {
          acc[0][c] += a0[kk] * w[c];
          acc[1][c] += a1[kk] * w[c];
        }
      }
    }
    #pragma unroll
    for (int rr = 0; rr < 2; ++rr) {
      H2[(rg * 2 + rr) * 132 + j0]     = fmaxf(acc[rr][0], 0.f);
      H2[(rg * 2 + rr) * 132 + j0 + 1] = fmaxf(acc[rr][1], 0.f);
      H2[(rg * 2 + rr) * 132 + j0 + 2] = fmaxf(acc[rr][2], 0.f);
      H2[(rg * 2 + rr) * 132 + j0 + 3] = fmaxf(acc[rr][3], 0.f);
    }
  }
  __syncthreads();
  // attn2 weights (x_2) for own 32 rows
  {
    float x0 = xall[2 * DIM + lane * 2], x1 = xall[2 * DIM + lane * 2 + 1];
    for (int rr = 0; rr < 4; ++rr) {
      int row = wv * 4 + rr;
      float2 h = *(float2*)&H2[row * 132 + lane * 2];
      float p = h.x * x0 + h.y * x1;
      #pragma unroll
      for (int s = 32; s > 0; s >>= 1) p += __shfl_xor(p, s, 64);
      if (lane == 0) w54[row] = tanhf(p);
    }
  }
  __syncthreads();
  // colsum of w2[r]*H2[r] -> xp
  {
    int c = tid & 127, h = tid >> 7;
    float s = 0.f;
    #pragma unroll
    for (int q = 0; q < 8; ++q) {
      int r = h + q * 4;
      s += w54[r] * H2[r * 132 + c];
    }
    red[h * DIM + c] = s;
    __syncthreads();
    if (h == 0)
      atomicAdd(&xp[c], red[c] + red[DIM + c] + red[2 * DIM + c] + red[3 * DIM + c]);
  }
  // last-block final softmax
  __threadfence();
  __syncthreads();
  if (tid == 0) lastf = (atomicAdd(ctr, 1) == (int)gridDim.x - 1);
  __syncthreads();
  if (lastf) {
    __threadfence();
    float p0 = 0.f, p1 = 0.f;
    if (tid < 256) {
      float y = (tid < DIM) ? xc[tid] : atomicAdd(&xp[tid - DIM], 0.0f);
      p0 = y * Wo[tid];
      p1 = y * Wo[256 + tid];
    }
    #pragma unroll
    for (int s = 32; s > 0; s >>= 1) {
      p0 += __shfl_xor(p0, s, 64);
      p1 += __shfl_xor(p1, s, 64);
    }
    if (tid < 256 && lane == 0) { fs[wv] = p0; fs[16 + wv] = p1; }
    __syncthreads();
    if (tid == 0) {
      float l0v = bo[0], l1v = bo[1];
      #pragma unroll
      for (int w = 0; w < 4; ++w) { l0v += fs[w]; l1v += fs[16 + w]; }
      float m = fmaxf(l0v, l1v);
      float e0 = expf(l0v - m), e1 = expf(l1v - m);
      out[0] = e0 / (e0 + e1);
      out[1] = e1 / (e0 + e1);
    }
  }
}

// ============ host ============
extern "C" void kernel_launch(void* const* d_in, const int* in_sizes, int n_in,
                              void* d_out, int out_size, void* d_ws, size_t ws_size,
                              hipStream_t stream) {
  const int*   fp     = (const int*)d_in[0];
  const int*   words  = (const int*)d_in[1];
  const float* adj    = (const float*)d_in[2];
  const float* emb_fp = (const float*)d_in[3];
  const float* emb_w  = (const float*)d_in[4];
  const float* Wg     = (const float*)d_in[5];
  const float* bg     = (const float*)d_in[6];
  const float* cw     = (const float*)d_in[7];
  const float* cb     = (const float*)d_in[8];
  const float* Wa     = (const float*)d_in[9];
  const float* ba     = (const float*)d_in[10];
  const float* Wo     = (const float*)d_in[11];
  const float* bo     = (const float*)d_in[12];
  float* out = (float*)d_out;

  float* ws    = (float*)d_ws;
  float* xs    = ws;                      // A: atom features (updated in place)
  float* bufB  = ws + (size_t)NF;         // B: hs_0 (GNN), then hs2p1 (protein)
  float* bufC  = ws + 2 * (size_t)NF;     // C: xsp0 (gathered words), then hs_1
  float* bufD  = ws + 3 * (size_t)NF;     // D: hs2p0
  int*   ell   = (int*)(ws + 4 * (size_t)NF);
  int*   cnt   = ell + (size_t)NA * CAP;
  int*   degcol= cnt + NA;
  float* xc    = (float*)(degcol + NA);   // [128]
  float* xp    = xc + DIM;                // [128]
  float* xall  = xp + DIM;                // [3,128]
  float* WgT   = xall + 3 * DIM;          // [3,128,128]
  float* WaT   = WgT + 3 * DIM * DIM;     // [128,128]
  int*   ctrs  = (int*)(WaT + DIM * DIM); // [2]

  k_prep<<<dim3(2121), 256, 0, stream>>>(fp, words, emb_fp, emb_w, Wg, Wa,
                                         xs, bufC, WgT, WaT, xc, xp, degcol, ctrs);
  k_scan<<<dim3(1536), 512, 0, stream>>>(adj, WgT, bg, xs, bufB,
                                         bufC, cw, cb, WaT, ba, bufD,
                                         ell, cnt, degcol);
  k_gnn1<<<dim3(512), 512, 0, stream>>>(ell, cnt, bufB, xs,
                                        WgT + (size_t)DIM * DIM, bg + DIM, bufC);
  k_gnn2<<<dim3(512), 512, 0, stream>>>(ell, cnt, bufC, xs,
                                        WgT + 2 * (size_t)DIM * DIM, bg + 2 * DIM,
                                        degcol, xc, WaT, ba, xall, ctrs);
  k_prot1<<<dim3(256), 512, 0, stream>>>(bufD, xall, cw + 529, cb + 1,
                                         WaT, ba, bufB);
  k_prot2<<<dim3(256), 512, 0, stream>>>(bufB, xall, cw + 2 * 529, cb + 2,
                                         WaT, ba, xp, xc, Wo, bo, out, ctrs + 1);
}